// Round 2
// baseline (130.197 us; speedup 1.0000x reference)
//
#include <hip/hip_runtime.h>

// RaySamples: per-ray (K=128) exclusive scan of delta*density, then
//   T = exp(-acc_excl), w = T[k] - T[k+1]  (== alpha*T algebraically).
//
// R2 layout: 8 samples (2 float4) per lane -> 16 lanes per ray, 4 rays per
// wave64. Ray boundary on lane-16 boundary -> segmented scan via
// __shfl_up(width=16), 4 steps (vs 5). 9 exps per 8 samples (vs 5 per 4).
// Outputs via nontemporal stores (write-once, never re-read).
// Memory-bound: 134 MB total traffic, floor ~21 us @ 6.3 TB/s.

typedef float v4f __attribute__((ext_vector_type(4)));

__global__ __launch_bounds__(256) void RaySamples_34454227648765_kernel(
    const float* __restrict__ dens, const float* __restrict__ delt,
    float* __restrict__ outw, float* __restrict__ outT, int n8)
{
    int i = blockIdx.x * blockDim.x + threadIdx.x;  // 8-sample group index
    if (i >= n8) return;

    const v4f* d4 = (const v4f*)dens;
    const v4f* l4 = (const v4f*)delt;

    v4f d0 = d4[2 * i];
    v4f d1 = d4[2 * i + 1];
    v4f p0 = l4[2 * i];
    v4f p1 = l4[2 * i + 1];

    float dd[8];
    dd[0] = d0.x * p0.x; dd[1] = d0.y * p0.y;
    dd[2] = d0.z * p0.z; dd[3] = d0.w * p0.w;
    dd[4] = d1.x * p1.x; dd[5] = d1.y * p1.y;
    dd[6] = d1.z * p1.z; dd[7] = d1.w * p1.w;

    float s = ((dd[0] + dd[1]) + (dd[2] + dd[3])) +
              ((dd[4] + dd[5]) + (dd[6] + dd[7]));

    // Inclusive scan of per-lane totals across the 16-lane ray segment.
    int lane = threadIdx.x & 15;
    float inc = s;
    #pragma unroll
    for (int off = 1; off < 16; off <<= 1) {
        float v = __shfl_up(inc, off, 16);
        inc += (lane >= off) ? v : 0.0f;
    }

    // Exclusive prefixes within this lane's 8 samples.
    float a = inc - s;
    float t[9];
    #pragma unroll
    for (int j = 0; j < 8; ++j) {
        t[j] = __expf(-a);
        a += dd[j];
    }
    t[8] = __expf(-a);

    v4f T0 = {t[0], t[1], t[2], t[3]};
    v4f T1 = {t[4], t[5], t[6], t[7]};
    // w[k] = exp(-acc[k]) - exp(-acc[k+1])
    v4f W0 = {t[0] - t[1], t[1] - t[2], t[2] - t[3], t[3] - t[4]};
    v4f W1 = {t[4] - t[5], t[5] - t[6], t[6] - t[7], t[7] - t[8]};

    v4f* w4 = (v4f*)outw;
    v4f* T4 = (v4f*)outT;
    __builtin_nontemporal_store(W0, &w4[2 * i]);
    __builtin_nontemporal_store(W1, &w4[2 * i + 1]);
    __builtin_nontemporal_store(T0, &T4[2 * i]);
    __builtin_nontemporal_store(T1, &T4[2 * i + 1]);
}

extern "C" void kernel_launch(void* const* d_in, const int* in_sizes, int n_in,
                              void* d_out, int out_size, void* d_ws, size_t ws_size,
                              hipStream_t stream) {
    const float* dens = (const float*)d_in[0];   // densities [N,K,1] fp32
    const float* delt = (const float*)d_in[1];   // deltas    [N,K,1] fp32
    float* out = (float*)d_out;                  // [weights | transmittance]

    const int NK = in_sizes[0];                  // N*K = 8388608
    const int n8 = NK / 8;                       // 8-sample groups
    float* outw = out;
    float* outT = out + NK;

    const int block = 256;
    const int grid = (n8 + block - 1) / block;   // 4096 blocks
    RaySamples_34454227648765_kernel<<<grid, block, 0, stream>>>(
        dens, delt, outw, outT, n8);
}

// Round 3
// 115.165 us; speedup vs baseline: 1.1305x; 1.1305x over previous
//
#include <hip/hip_runtime.h>

// RaySamples: per-ray (K=128) exclusive scan of delta*density, then
//   T = exp(-acc_excl), w = T[k] - T[k+1]  (== alpha*T algebraically).
//
// Layout: 8 samples (2 float4) per lane -> 16 lanes per ray, 4 rays per
// wave64. Ray boundary on lane-16 boundary -> segmented scan via
// __shfl_up(width=16). Plain stores (NOT nontemporal: harness poisons
// d_out leaving dirty L2 lines; NT stores forced poison writeback + NT
// write = 2x WRITE_SIZE, measured R2 123 MB vs 67 MB actual output).
// Memory-bound: ~100 MB HBM traffic/iter (inputs half L3-hot), floor ~17 us.

typedef float v4f __attribute__((ext_vector_type(4)));

__global__ __launch_bounds__(256) void RaySamples_34454227648765_kernel(
    const float* __restrict__ dens, const float* __restrict__ delt,
    float* __restrict__ outw, float* __restrict__ outT, int n8)
{
    int i = blockIdx.x * blockDim.x + threadIdx.x;  // 8-sample group index
    if (i >= n8) return;

    const v4f* d4 = (const v4f*)dens;
    const v4f* l4 = (const v4f*)delt;

    v4f d0 = d4[2 * i];
    v4f d1 = d4[2 * i + 1];
    v4f p0 = l4[2 * i];
    v4f p1 = l4[2 * i + 1];

    float dd[8];
    dd[0] = d0.x * p0.x; dd[1] = d0.y * p0.y;
    dd[2] = d0.z * p0.z; dd[3] = d0.w * p0.w;
    dd[4] = d1.x * p1.x; dd[5] = d1.y * p1.y;
    dd[6] = d1.z * p1.z; dd[7] = d1.w * p1.w;

    float s = ((dd[0] + dd[1]) + (dd[2] + dd[3])) +
              ((dd[4] + dd[5]) + (dd[6] + dd[7]));

    // Inclusive scan of per-lane totals across the 16-lane ray segment.
    int lane = threadIdx.x & 15;
    float inc = s;
    #pragma unroll
    for (int off = 1; off < 16; off <<= 1) {
        float v = __shfl_up(inc, off, 16);
        inc += (lane >= off) ? v : 0.0f;
    }

    // Exclusive prefixes within this lane's 8 samples.
    float a = inc - s;
    float t[9];
    #pragma unroll
    for (int j = 0; j < 8; ++j) {
        t[j] = __expf(-a);
        a += dd[j];
    }
    t[8] = __expf(-a);

    v4f T0 = {t[0], t[1], t[2], t[3]};
    v4f T1 = {t[4], t[5], t[6], t[7]};
    // w[k] = exp(-acc[k]) - exp(-acc[k+1])
    v4f W0 = {t[0] - t[1], t[1] - t[2], t[2] - t[3], t[3] - t[4]};
    v4f W1 = {t[4] - t[5], t[5] - t[6], t[6] - t[7], t[7] - t[8]};

    v4f* w4 = (v4f*)outw;
    v4f* T4 = (v4f*)outT;
    w4[2 * i]     = W0;
    w4[2 * i + 1] = W1;
    T4[2 * i]     = T0;
    T4[2 * i + 1] = T1;
}

extern "C" void kernel_launch(void* const* d_in, const int* in_sizes, int n_in,
                              void* d_out, int out_size, void* d_ws, size_t ws_size,
                              hipStream_t stream) {
    const float* dens = (const float*)d_in[0];   // densities [N,K,1] fp32
    const float* delt = (const float*)d_in[1];   // deltas    [N,K,1] fp32
    float* out = (float*)d_out;                  // [weights | transmittance]

    const int NK = in_sizes[0];                  // N*K = 8388608
    const int n8 = NK / 8;                       // 8-sample groups
    float* outw = out;
    float* outT = out + NK;

    const int block = 256;
    const int grid = (n8 + block - 1) / block;   // 4096 blocks
    RaySamples_34454227648765_kernel<<<grid, block, 0, stream>>>(
        dens, delt, outw, outT, n8);
}

// Round 4
// 113.333 us; speedup vs baseline: 1.1488x; 1.0162x over previous
//
#include <hip/hip_runtime.h>

// RaySamples: per-ray (K=128) exclusive scan of delta*density, then
//   T = exp(-acc_excl), w = T[k] - T[k+1]  (== alpha*T algebraically).
//
// R4: 8 samples/lane for memory parallelism (4 loads in flight), but with
// WAVE-CONTIGUOUS instructions: thread t of block b handles v4f indices
// b*512+t and b*512+t+256, so every load/store instr is 64 lanes x 16 B
// contiguous (R3's 2i/2i+1 interleave touched each 64B line twice ->
// doubled L2 requests, +4 us). Both streams' ray boundaries align to
// lane-32 groups -> two independent width-32 segmented shuffle scans.
// Plain stores (NT stores forced poison-line writeback: R2 WRITE_SIZE
// 123 MB vs 67 MB actual). Memory-bound: ~100 MB HBM/iter, floor ~17 us.

typedef float v4f __attribute__((ext_vector_type(4)));

__global__ __launch_bounds__(256) void RaySamples_34454227648765_kernel(
    const float* __restrict__ dens, const float* __restrict__ delt,
    float* __restrict__ outw, float* __restrict__ outT, int n4)
{
    const int tid = threadIdx.x;
    const int i0 = blockIdx.x * 512 + tid;        // v4f index, stream 0
    const int i1 = i0 + 256;                      // v4f index, stream 1
    if (i1 >= n4) {
        // tail-safe (not hit for N*K = 8M): fall back per-stream
        if (i0 >= n4) return;
    }

    const v4f* d4 = (const v4f*)dens;
    const v4f* l4 = (const v4f*)delt;

    v4f da = d4[i0];
    v4f db = d4[i1];
    v4f pa = l4[i0];
    v4f pb = l4[i1];

    float A[4], B[4];
    A[0] = da.x * pa.x; A[1] = da.y * pa.y; A[2] = da.z * pa.z; A[3] = da.w * pa.w;
    B[0] = db.x * pb.x; B[1] = db.y * pb.y; B[2] = db.z * pb.z; B[3] = db.w * pb.w;

    float sa = (A[0] + A[1]) + (A[2] + A[3]);
    float sb = (B[0] + B[1]) + (B[2] + B[3]);

    // Two independent width-32 segmented inclusive scans (interleaved ILP).
    const int lane = tid & 31;
    float ia = sa, ib = sb;
    #pragma unroll
    for (int off = 1; off < 32; off <<= 1) {
        float va = __shfl_up(ia, off, 32);
        float vb = __shfl_up(ib, off, 32);
        bool ok = (lane >= off);
        ia += ok ? va : 0.0f;
        ib += ok ? vb : 0.0f;
    }

    // Exclusive prefixes within this lane's 4 samples, per stream.
    float aa = ia - sa;
    float ab = ib - sb;
    float ta[5], tb[5];
    #pragma unroll
    for (int j = 0; j < 4; ++j) {
        ta[j] = __expf(-aa); aa += A[j];
        tb[j] = __expf(-ab); ab += B[j];
    }
    ta[4] = __expf(-aa);
    tb[4] = __expf(-ab);

    v4f Ta = {ta[0], ta[1], ta[2], ta[3]};
    v4f Tb = {tb[0], tb[1], tb[2], tb[3]};
    // w[k] = exp(-acc[k]) - exp(-acc[k+1])
    v4f Wa = {ta[0] - ta[1], ta[1] - ta[2], ta[2] - ta[3], ta[3] - ta[4]};
    v4f Wb = {tb[0] - tb[1], tb[1] - tb[2], tb[2] - tb[3], tb[3] - tb[4]};

    v4f* w4 = (v4f*)outw;
    v4f* T4 = (v4f*)outT;
    w4[i0] = Wa;
    w4[i1] = Wb;
    T4[i0] = Ta;
    T4[i1] = Tb;
}

extern "C" void kernel_launch(void* const* d_in, const int* in_sizes, int n_in,
                              void* d_out, int out_size, void* d_ws, size_t ws_size,
                              hipStream_t stream) {
    const float* dens = (const float*)d_in[0];   // densities [N,K,1] fp32
    const float* delt = (const float*)d_in[1];   // deltas    [N,K,1] fp32
    float* out = (float*)d_out;                  // [weights | transmittance]

    const int NK = in_sizes[0];                  // N*K = 8388608
    const int n4 = NK / 4;                       // float4 quads (2M)
    float* outw = out;
    float* outT = out + NK;

    const int block = 256;
    const int grid = n4 / 512;                   // 4096 blocks, 512 v4f each
    RaySamples_34454227648765_kernel<<<grid, block, 0, stream>>>(
        dens, delt, outw, outT, n4);
}

// Round 5
// 111.725 us; speedup vs baseline: 1.1653x; 1.0144x over previous
//
#include <hip/hip_runtime.h>

// RaySamples: per-ray (K=128) exclusive scan of delta*density, then
//   T = exp(-acc_excl), w = T[k] - T[k+1]  (== alpha*T algebraically).
//
// R5: MLP-depth experiment. 4 wave-contiguous streams per thread
// (v4f indices blk*1024 + tid + 256*s), 8 x 16B loads in flight per wave
// (8 KB) at unchanged resident-wave count -> 2x total outstanding bytes
// vs R1/R4. Distinguishes latency-limited (win) vs fabric-plateau
// (neutral -> roofline). Segment boundaries stay lane-32-aligned
// (256*s % 32 == 0) -> 4 interleaved width-32 segmented scans.
// Plain stores (NT stores doubled WRITE_SIZE via poison-line writeback, R2).

typedef float v4f __attribute__((ext_vector_type(4)));

__global__ __launch_bounds__(256) void RaySamples_34454227648765_kernel(
    const float* __restrict__ dens, const float* __restrict__ delt,
    float* __restrict__ outw, float* __restrict__ outT)
{
    const int tid  = threadIdx.x;
    const int base = blockIdx.x * 1024 + tid;     // v4f index of stream 0

    const v4f* d4 = (const v4f*)dens;
    const v4f* l4 = (const v4f*)delt;

    // Issue all 8 loads up front (max memory-level parallelism).
    v4f d[4], p[4];
    #pragma unroll
    for (int s = 0; s < 4; ++s) d[s] = d4[base + 256 * s];
    #pragma unroll
    for (int s = 0; s < 4; ++s) p[s] = l4[base + 256 * s];

    float dd[4][4], sum[4];
    #pragma unroll
    for (int s = 0; s < 4; ++s) {
        dd[s][0] = d[s].x * p[s].x;
        dd[s][1] = d[s].y * p[s].y;
        dd[s][2] = d[s].z * p[s].z;
        dd[s][3] = d[s].w * p[s].w;
        sum[s] = (dd[s][0] + dd[s][1]) + (dd[s][2] + dd[s][3]);
    }

    // 4 interleaved width-32 segmented inclusive scans.
    const int lane = tid & 31;
    float inc[4] = {sum[0], sum[1], sum[2], sum[3]};
    #pragma unroll
    for (int off = 1; off < 32; off <<= 1) {
        float v0 = __shfl_up(inc[0], off, 32);
        float v1 = __shfl_up(inc[1], off, 32);
        float v2 = __shfl_up(inc[2], off, 32);
        float v3 = __shfl_up(inc[3], off, 32);
        bool ok = (lane >= off);
        inc[0] += ok ? v0 : 0.0f;
        inc[1] += ok ? v1 : 0.0f;
        inc[2] += ok ? v2 : 0.0f;
        inc[3] += ok ? v3 : 0.0f;
    }

    v4f* w4 = (v4f*)outw;
    v4f* T4 = (v4f*)outT;

    #pragma unroll
    for (int s = 0; s < 4; ++s) {
        float a = inc[s] - sum[s];                // exclusive prefix
        float t[5];
        #pragma unroll
        for (int j = 0; j < 4; ++j) {
            t[j] = __expf(-a);
            a += dd[s][j];
        }
        t[4] = __expf(-a);

        v4f T = {t[0], t[1], t[2], t[3]};
        // w[k] = exp(-acc[k]) - exp(-acc[k+1])
        v4f W = {t[0] - t[1], t[1] - t[2], t[2] - t[3], t[3] - t[4]};
        w4[base + 256 * s] = W;
        T4[base + 256 * s] = T;
    }
}

extern "C" void kernel_launch(void* const* d_in, const int* in_sizes, int n_in,
                              void* d_out, int out_size, void* d_ws, size_t ws_size,
                              hipStream_t stream) {
    const float* dens = (const float*)d_in[0];   // densities [N,K,1] fp32
    const float* delt = (const float*)d_in[1];   // deltas    [N,K,1] fp32
    float* out = (float*)d_out;                  // [weights | transmittance]

    const int NK = in_sizes[0];                  // N*K = 8388608
    const int n4 = NK / 4;                       // 2M float4 quads
    float* outw = out;
    float* outT = out + NK;

    const int block = 256;
    const int grid = n4 / 1024;                  // 2048 blocks, 1024 v4f each
    RaySamples_34454227648765_kernel<<<grid, block, 0, stream>>>(
        dens, delt, outw, outT);
}